// Round 1
// baseline (9416.215 us; speedup 1.0000x reference)
//
#include <hip/hip_runtime.h>
#include <cstddef>

#define TPB 256
#define BN_RS 0.99999500003749971f  // 1/sqrt(1+1e-5)

// ---------------- elementwise batchnorm (eval mode) ----------------
__global__ void bn_kernel(const float* __restrict__ in, const float* __restrict__ gamma,
                          const float* __restrict__ beta, float* __restrict__ out, int n4) {
    int i = blockIdx.x * blockDim.x + threadIdx.x;
    if (i >= n4) return;
    float4 v = ((const float4*)in)[i];
    float4 g = ((const float4*)gamma)[i & 7];
    float4 b = ((const float4*)beta)[i & 7];
    v.x = fmaf(v.x, g.x * BN_RS, b.x);
    v.y = fmaf(v.y, g.y * BN_RS, b.y);
    v.z = fmaf(v.z, g.z * BN_RS, b.z);
    v.w = fmaf(v.w, g.w * BN_RS, b.w);
    ((float4*)out)[i] = v;
}

// ---------------- segment counts (deg / gcnt) ----------------
__global__ void count_kernel(const int* __restrict__ idx, float* __restrict__ cnt, int n) {
    int i = blockIdx.x * blockDim.x + threadIdx.x;
    if (i < n) atomicAdd(&cnt[idx[i]], 1.0f);
}

// ---------------- MLP helpers (weights in LDS, h[64] in VGPRs) ----------------
__device__ __forceinline__ void accum_k(float a, const float* __restrict__ w, float* h) {
#pragma unroll
    for (int j = 0; j < 64; j += 4) {
        float4 wv = *(const float4*)(w + j);
        h[j + 0] = fmaf(a, wv.x, h[j + 0]);
        h[j + 1] = fmaf(a, wv.y, h[j + 1]);
        h[j + 2] = fmaf(a, wv.z, h[j + 2]);
        h[j + 3] = fmaf(a, wv.w, h[j + 3]);
    }
}

// accumulate one 32-wide input segment (rows w0[k*64 + j]) scaled by `scale`
__device__ __forceinline__ void accum_seg(const float* __restrict__ p, float scale,
                                          const float* __restrict__ w0, float* h) {
#pragma unroll 1
    for (int q = 0; q < 8; ++q) {
        float4 v = *(const float4*)(p + 4 * q);
        accum_k(v.x * scale, w0 + (4 * q + 0) * 64, h);
        accum_k(v.y * scale, w0 + (4 * q + 1) * 64, h);
        accum_k(v.z * scale, w0 + (4 * q + 2) * 64, h);
        accum_k(v.w * scale, w0 + (4 * q + 3) * 64, h);
    }
}

// same, but apply eval-mode BN affine to the segment first (layer-0 edge feats)
__device__ __forceinline__ void accum_seg_bn(const float* __restrict__ p,
                                             const float* __restrict__ gamma,
                                             const float* __restrict__ beta,
                                             const float* __restrict__ w0, float* h) {
#pragma unroll 1
    for (int q = 0; q < 8; ++q) {
        float4 v = *(const float4*)(p + 4 * q);
        float4 g = *(const float4*)(gamma + 4 * q);
        float4 b = *(const float4*)(beta + 4 * q);
        v.x = fmaf(v.x, g.x * BN_RS, b.x);
        v.y = fmaf(v.y, g.y * BN_RS, b.y);
        v.z = fmaf(v.z, g.z * BN_RS, b.z);
        v.w = fmaf(v.w, g.w * BN_RS, b.w);
        accum_k(v.x, w0 + (4 * q + 0) * 64, h);
        accum_k(v.y, w0 + (4 * q + 1) * 64, h);
        accum_k(v.z, w0 + (4 * q + 2) * 64, h);
        accum_k(v.w, w0 + (4 * q + 3) * 64, h);
    }
}

// ---------------- edge model: e' = MLP([x_src, x_dst, e, u[batch_src]]) + scatter-sum to agg ----------------
__global__ __launch_bounds__(TPB) void edge_kernel(
    const float* __restrict__ x, const float* __restrict__ e_in, float* __restrict__ e_out,
    const float* __restrict__ u, const int* __restrict__ ei_src, const int* __restrict__ ei_dst,
    const int* __restrict__ batch,
    const float* __restrict__ W1, const float* __restrict__ b1,
    const float* __restrict__ W2, const float* __restrict__ b2,
    const float* __restrict__ egamma, const float* __restrict__ ebeta, int bn_e,
    float* __restrict__ agg, int E) {
    __shared__ float sW1[128 * 64];
    __shared__ float sW2[64 * 32];
    __shared__ float sb1[64];
    __shared__ float sb2[32];
    for (int i = threadIdx.x; i < 128 * 64; i += TPB) sW1[i] = W1[i];
    for (int i = threadIdx.x; i < 64 * 32; i += TPB) sW2[i] = W2[i];
    if (threadIdx.x < 64) sb1[threadIdx.x] = b1[threadIdx.x];
    if (threadIdx.x < 32) sb2[threadIdx.x] = b2[threadIdx.x];
    __syncthreads();

    int eid = blockIdx.x * TPB + threadIdx.x;
    if (eid >= E) return;

    int s = ei_src[eid];
    int d = ei_dst[eid];
    int bb = batch[s];

    float h[64];
#pragma unroll
    for (int j = 0; j < 64; ++j) h[j] = sb1[j];

    accum_seg(x + (size_t)s * 32, 1.0f, sW1 + 0 * 64, h);
    accum_seg(x + (size_t)d * 32, 1.0f, sW1 + 32 * 64, h);
    if (bn_e)
        accum_seg_bn(e_in + (size_t)eid * 32, egamma, ebeta, sW1 + 64 * 64, h);
    else
        accum_seg(e_in + (size_t)eid * 32, 1.0f, sW1 + 64 * 64, h);
    accum_seg(u + (size_t)bb * 32, 1.0f, sW1 + 96 * 64, h);

    float o[32];
#pragma unroll
    for (int j = 0; j < 32; ++j) o[j] = sb2[j];
#pragma unroll
    for (int k = 0; k < 64; ++k) {
        float a = fmaxf(h[k], 0.0f);
        const float* w = sW2 + k * 32;
#pragma unroll
        for (int j = 0; j < 32; j += 4) {
            float4 wv = *(const float4*)(w + j);
            o[j + 0] = fmaf(a, wv.x, o[j + 0]);
            o[j + 1] = fmaf(a, wv.y, o[j + 1]);
            o[j + 2] = fmaf(a, wv.z, o[j + 2]);
            o[j + 3] = fmaf(a, wv.w, o[j + 3]);
        }
    }

    float4* eo = (float4*)(e_out + (size_t)eid * 32);
#pragma unroll
    for (int q = 0; q < 8; ++q)
        eo[q] = make_float4(o[4 * q], o[4 * q + 1], o[4 * q + 2], o[4 * q + 3]);

    float* ag = agg + (size_t)d * 32;
#pragma unroll
    for (int j = 0; j < 32; ++j) atomicAdd(ag + j, o[j]);
}

// ---------------- node model: x' = MLP([x, agg/deg, u[batch]]) + scatter-sum to xg ----------------
__global__ __launch_bounds__(TPB) void node_kernel(
    float* __restrict__ x, const float* __restrict__ agg, const float* __restrict__ deg,
    const float* __restrict__ u, const int* __restrict__ batch,
    const float* __restrict__ W1, const float* __restrict__ b1,
    const float* __restrict__ W2, const float* __restrict__ b2,
    float* __restrict__ xg, int N) {
    __shared__ float sW1[96 * 64];
    __shared__ float sW2[64 * 32];
    __shared__ float sb1[64];
    __shared__ float sb2[32];
    for (int i = threadIdx.x; i < 96 * 64; i += TPB) sW1[i] = W1[i];
    for (int i = threadIdx.x; i < 64 * 32; i += TPB) sW2[i] = W2[i];
    if (threadIdx.x < 64) sb1[threadIdx.x] = b1[threadIdx.x];
    if (threadIdx.x < 32) sb2[threadIdx.x] = b2[threadIdx.x];
    __syncthreads();

    int i = blockIdx.x * TPB + threadIdx.x;
    if (i >= N) return;

    int bb = batch[i];
    float rdeg = 1.0f / fmaxf(deg[i], 1.0f);

    float h[64];
#pragma unroll
    for (int j = 0; j < 64; ++j) h[j] = sb1[j];

    accum_seg(x + (size_t)i * 32, 1.0f, sW1 + 0 * 64, h);
    accum_seg(agg + (size_t)i * 32, rdeg, sW1 + 32 * 64, h);
    accum_seg(u + (size_t)bb * 32, 1.0f, sW1 + 64 * 64, h);

    float o[32];
#pragma unroll
    for (int j = 0; j < 32; ++j) o[j] = sb2[j];
#pragma unroll
    for (int k = 0; k < 64; ++k) {
        float a = fmaxf(h[k], 0.0f);
        const float* w = sW2 + k * 32;
#pragma unroll
        for (int j = 0; j < 32; j += 4) {
            float4 wv = *(const float4*)(w + j);
            o[j + 0] = fmaf(a, wv.x, o[j + 0]);
            o[j + 1] = fmaf(a, wv.y, o[j + 1]);
            o[j + 2] = fmaf(a, wv.z, o[j + 2]);
            o[j + 3] = fmaf(a, wv.w, o[j + 3]);
        }
    }

    float4* xo = (float4*)(x + (size_t)i * 32);
#pragma unroll
    for (int q = 0; q < 8; ++q)
        xo[q] = make_float4(o[4 * q], o[4 * q + 1], o[4 * q + 2], o[4 * q + 3]);

    float* xgp = xg + (size_t)bb * 32;
#pragma unroll
    for (int j = 0; j < 32; ++j) atomicAdd(xgp + j, o[j]);
}

// ---------------- global model: u' = MLP([u, xg/gcnt]) ----------------
__global__ void glob_kernel(const float* __restrict__ u, const float* __restrict__ xg,
                            const float* __restrict__ gcnt,
                            const float* __restrict__ W1, const float* __restrict__ b1,
                            const float* __restrict__ W2, const float* __restrict__ b2,
                            float* __restrict__ u_dst) {
    int r = blockIdx.x;
    int t = threadIdx.x;  // 64 threads = 1 wave
    __shared__ float gin[64];
    __shared__ float hs[64];
    if (t < 32)
        gin[t] = u[r * 32 + t];
    else
        gin[t] = xg[r * 32 + (t - 32)] / fmaxf(gcnt[r], 1.0f);
    __syncthreads();
    float h = b1[t];
#pragma unroll
    for (int k = 0; k < 64; ++k) h = fmaf(gin[k], W1[k * 64 + t], h);
    hs[t] = fmaxf(h, 0.0f);
    __syncthreads();
    if (t < 32) {
        float o = b2[t];
#pragma unroll
        for (int k = 0; k < 64; ++k) o = fmaf(hs[k], W2[k * 32 + t], o);
        u_dst[r * 32 + t] = o;
    }
}

extern "C" void kernel_launch(void* const* d_in, const int* in_sizes, int n_in,
                              void* d_out, int out_size, void* d_ws, size_t ws_size,
                              hipStream_t stream) {
    const float* node_feats = (const float*)d_in[0];
    const int* edge_index = (const int*)d_in[1];
    const float* edge_feats = (const float*)d_in[2];
    const float* glob_feats = (const float*)d_in[3];
    const int* batch = (const int*)d_in[4];
    const float* node_gamma = (const float*)d_in[5];
    const float* node_beta = (const float*)d_in[6];
    const float* edge_gamma = (const float*)d_in[7];
    const float* edge_beta = (const float*)d_in[8];
    const float* glob_gamma = (const float*)d_in[9];
    const float* glob_beta = (const float*)d_in[10];
    const float* edge_W1 = (const float*)d_in[11];
    const float* edge_b1 = (const float*)d_in[12];
    const float* edge_W2 = (const float*)d_in[13];
    const float* edge_b2 = (const float*)d_in[14];
    const float* node_W1 = (const float*)d_in[15];
    const float* node_b1 = (const float*)d_in[16];
    const float* node_W2 = (const float*)d_in[17];
    const float* node_b2 = (const float*)d_in[18];
    const float* glob_W1 = (const float*)d_in[19];
    const float* glob_b1 = (const float*)d_in[20];
    const float* glob_W2 = (const float*)d_in[21];
    const float* glob_b2 = (const float*)d_in[22];

    const int N = in_sizes[0] / 32;
    const int E = in_sizes[1] / 2;
    const int B = in_sizes[3] / 32;

    float* x_out = (float*)d_out;                 // N x 32
    float* e_out = x_out + (size_t)N * 32;        // E x 32
    float* u_out = e_out + (size_t)E * 32;        // B x 32

    char* ws = (char*)d_ws;
    float* agg = (float*)ws;   ws += (size_t)N * 32 * 4;
    float* deg = (float*)ws;   ws += (size_t)N * 4;
    float* xg = (float*)ws;    ws += (size_t)B * 32 * 4;
    float* gcnt = (float*)ws;  ws += (size_t)B * 4;
    float* u_buf = (float*)ws; ws += (size_t)B * 32 * 4;

    const int* ei_src = edge_index;
    const int* ei_dst = edge_index + E;

    hipMemsetAsync(deg, 0, (size_t)N * 4, stream);
    hipMemsetAsync(gcnt, 0, (size_t)B * 4, stream);

    {
        int n4 = N * 32 / 4;
        bn_kernel<<<(n4 + TPB - 1) / TPB, TPB, 0, stream>>>(node_feats, node_gamma, node_beta, x_out, n4);
    }
    {
        int n4 = B * 32 / 4;
        bn_kernel<<<(n4 + TPB - 1) / TPB, TPB, 0, stream>>>(glob_feats, glob_gamma, glob_beta, u_buf, n4);
    }
    count_kernel<<<(E + TPB - 1) / TPB, TPB, 0, stream>>>(ei_dst, deg, E);
    count_kernel<<<(N + TPB - 1) / TPB, TPB, 0, stream>>>(batch, gcnt, N);

    for (int l = 0; l < 3; ++l) {
        hipMemsetAsync(agg, 0, (size_t)N * 32 * 4, stream);
        hipMemsetAsync(xg, 0, (size_t)B * 32 * 4, stream);
        edge_kernel<<<(E + TPB - 1) / TPB, TPB, 0, stream>>>(
            x_out, (l == 0) ? edge_feats : e_out, e_out, u_buf, ei_src, ei_dst, batch,
            edge_W1 + (size_t)l * 128 * 64, edge_b1 + l * 64,
            edge_W2 + (size_t)l * 64 * 32, edge_b2 + l * 32,
            edge_gamma, edge_beta, (l == 0) ? 1 : 0, agg, E);
        node_kernel<<<(N + TPB - 1) / TPB, TPB, 0, stream>>>(
            x_out, agg, deg, u_buf, batch,
            node_W1 + (size_t)l * 96 * 64, node_b1 + l * 64,
            node_W2 + (size_t)l * 64 * 32, node_b2 + l * 32,
            xg, N);
        glob_kernel<<<B, 64, 0, stream>>>(
            u_buf, xg, gcnt,
            glob_W1 + (size_t)l * 64 * 64, glob_b1 + l * 64,
            glob_W2 + (size_t)l * 64 * 32, glob_b2 + l * 32,
            (l == 2) ? u_out : u_buf);
    }
}

// Round 2
// 1095.859 us; speedup vs baseline: 8.5925x; 8.5925x over previous
//
#include <hip/hip_runtime.h>
#include <cstddef>

#define BN_RS 0.99999500003749971f  // 1/sqrt(1+1e-5)

typedef __attribute__((ext_vector_type(8))) short bf16x8;
typedef __attribute__((ext_vector_type(4))) float f32x4;

__device__ __forceinline__ short f2bf(float f) {
    union { float f; unsigned u; } c; c.f = f;
    unsigned r = (c.u + 0x7fffu + ((c.u >> 16) & 1u)) >> 16;
    return (short)r;
}

__device__ __forceinline__ bf16x8 load8_bf(const float* __restrict__ p) {
    float4 a = *(const float4*)p;
    float4 b = *(const float4*)(p + 4);
    bf16x8 r;
    r[0] = f2bf(a.x); r[1] = f2bf(a.y); r[2] = f2bf(a.z); r[3] = f2bf(a.w);
    r[4] = f2bf(b.x); r[5] = f2bf(b.y); r[6] = f2bf(b.z); r[7] = f2bf(b.w);
    return r;
}

// ---------------- elementwise batchnorm (eval mode) ----------------
__global__ void bn_kernel(const float* __restrict__ in, const float* __restrict__ gamma,
                          const float* __restrict__ beta, float* __restrict__ out, int n4) {
    int i = blockIdx.x * blockDim.x + threadIdx.x;
    if (i >= n4) return;
    float4 v = ((const float4*)in)[i];
    float4 g = ((const float4*)gamma)[i & 7];
    float4 b = ((const float4*)beta)[i & 7];
    v.x = fmaf(v.x, g.x * BN_RS, b.x);
    v.y = fmaf(v.y, g.y * BN_RS, b.y);
    v.z = fmaf(v.z, g.z * BN_RS, b.z);
    v.w = fmaf(v.w, g.w * BN_RS, b.w);
    ((float4*)out)[i] = v;
}

// ---------------- CSR build ----------------
__global__ void hist_kernel(const int* __restrict__ idx, int* __restrict__ cnt, int n) {
    int i = blockIdx.x * blockDim.x + threadIdx.x;
    if (i < n) atomicAdd(&cnt[idx[i]], 1);
}

__global__ void scan_kernel(const int* __restrict__ cnt, int* __restrict__ row, int N) {
    __shared__ int sd[1024];
    __shared__ int carry;
    if (threadIdx.x == 0) carry = 0;
    __syncthreads();
    for (int base = 0; base < N; base += 1024) {
        int i = base + (int)threadIdx.x;
        int v = (i < N) ? cnt[i] : 0;
        sd[threadIdx.x] = v;
        __syncthreads();
        for (int off = 1; off < 1024; off <<= 1) {
            int t = (threadIdx.x >= (unsigned)off) ? sd[threadIdx.x - off] : 0;
            __syncthreads();
            sd[threadIdx.x] += t;
            __syncthreads();
        }
        if (i < N) row[i] = carry + sd[threadIdx.x] - v;
        __syncthreads();
        if (threadIdx.x == 0) carry += sd[1023];
        __syncthreads();
    }
    if (threadIdx.x == 0) row[N] = carry;
}

__global__ void scatter_kernel(const int* __restrict__ dst, int* __restrict__ cursor,
                               int* __restrict__ eid, int E) {
    int e = blockIdx.x * blockDim.x + threadIdx.x;
    if (e < E) {
        int d = dst[e];
        int slot = atomicAdd(&cursor[d], 1);
        eid[slot] = e;
    }
}

// ---------------- agg = scatter_mean(e' -> dst) via CSR gather ----------------
__global__ void agg_kernel(const int* __restrict__ row, const int* __restrict__ eid,
                           const float* __restrict__ eo, float* __restrict__ aggm, int N) {
    int t = blockIdx.x * blockDim.x + threadIdx.x;
    int node = t >> 3;
    int c = (t & 7) * 4;
    if (node >= N) return;
    int s = row[node], e = row[node + 1];
    float4 acc = make_float4(0.f, 0.f, 0.f, 0.f);
    for (int j = s; j < e; ++j) {
        int ed = eid[j];
        float4 v = *(const float4*)(eo + (size_t)ed * 32 + c);
        acc.x += v.x; acc.y += v.y; acc.z += v.z; acc.w += v.w;
    }
    float inv = 1.0f / fmaxf((float)(e - s), 1.0f);
    acc.x *= inv; acc.y *= inv; acc.z *= inv; acc.w *= inv;
    *(float4*)(aggm + (size_t)node * 32 + c) = acc;
}

// ---------------- edge model (MFMA): e' = MLP([x_src, x_dst, e, u[batch_src]]) ----------------
__global__ __launch_bounds__(256) void edge_mfma(
    const float* __restrict__ x, const float* __restrict__ e_in, float* __restrict__ e_out,
    const float* __restrict__ u, const int* __restrict__ src, const int* __restrict__ dstp,
    const int* __restrict__ batch,
    const float* __restrict__ W1, const float* __restrict__ b1,
    const float* __restrict__ W2, const float* __restrict__ b2,
    const float* __restrict__ egam, const float* __restrict__ ebet, int bn_e, int E) {
    __shared__ short hbuf[4][16 * 72];  // per-wave h tile, padded stride 72
    const int tid = threadIdx.x;
    const int wv = tid >> 6, lane = tid & 63;
    const int n = lane & 15, q = lane >> 4;

    // register-resident weight fragments (B-operand: B[k][n], k = 8q+j)
    bf16x8 w1f[4][4];
#pragma unroll
    for (int s = 0; s < 4; ++s)
#pragma unroll
        for (int t = 0; t < 4; ++t)
#pragma unroll
            for (int j = 0; j < 8; ++j)
                w1f[s][t][j] = f2bf(W1[(32 * s + 8 * q + j) * 64 + 16 * t + n]);
    bf16x8 w2f[2][2];
#pragma unroll
    for (int s = 0; s < 2; ++s)
#pragma unroll
        for (int t = 0; t < 2; ++t)
#pragma unroll
            for (int j = 0; j < 8; ++j)
                w2f[s][t][j] = f2bf(W2[(32 * s + 8 * q + j) * 32 + 16 * t + n]);
    float b1v[4];
#pragma unroll
    for (int t = 0; t < 4; ++t) b1v[t] = b1[16 * t + n];
    float b2v[2];
#pragma unroll
    for (int t = 0; t < 2; ++t) b2v[t] = b2[16 * t + n];
    float egf[8], ebf[8];
    if (bn_e) {
#pragma unroll
        for (int j = 0; j < 8; ++j) {
            egf[j] = egam[8 * q + j] * BN_RS;
            ebf[j] = ebet[8 * q + j];
        }
    }

    short* hw = hbuf[wv];
#pragma unroll 1
    for (int t4 = 0; t4 < 4; ++t4) {
        int ebase = blockIdx.x * 256 + wv * 64 + t4 * 16;
        int eidx = min(ebase + n, E - 1);
        int si = src[eidx], di = dstp[eidx];
        int bi = batch[si];

        bf16x8 af[4];
        af[0] = load8_bf(x + (size_t)si * 32 + 8 * q);
        af[1] = load8_bf(x + (size_t)di * 32 + 8 * q);
        if (bn_e) {
            const float* p = e_in + (size_t)eidx * 32 + 8 * q;
            float4 a = *(const float4*)p;
            float4 b = *(const float4*)(p + 4);
            float v[8] = {a.x, a.y, a.z, a.w, b.x, b.y, b.z, b.w};
#pragma unroll
            for (int j = 0; j < 8; ++j) af[2][j] = f2bf(fmaf(v[j], egf[j], ebf[j]));
        } else {
            af[2] = load8_bf(e_in + (size_t)eidx * 32 + 8 * q);
        }
        af[3] = load8_bf(u + (size_t)bi * 32 + 8 * q);

        f32x4 acc[4];
#pragma unroll
        for (int t = 0; t < 4; ++t) acc[t] = (f32x4){b1v[t], b1v[t], b1v[t], b1v[t]};
#pragma unroll
        for (int s = 0; s < 4; ++s)
#pragma unroll
            for (int t = 0; t < 4; ++t)
                acc[t] = __builtin_amdgcn_mfma_f32_16x16x32_bf16(af[s], w1f[s][t], acc[t], 0, 0, 0);

        __syncthreads();  // previous tile's h reads done before overwrite
#pragma unroll
        for (int t = 0; t < 4; ++t)
#pragma unroll
            for (int r = 0; r < 4; ++r)
                hw[(4 * q + r) * 72 + 16 * t + n] = f2bf(fmaxf(acc[t][r], 0.0f));
        __syncthreads();

        bf16x8 a2[2];
#pragma unroll
        for (int s = 0; s < 2; ++s)
            a2[s] = *(const bf16x8*)(hw + n * 72 + 32 * s + 8 * q);

        f32x4 acc2[2];
#pragma unroll
        for (int t = 0; t < 2; ++t) acc2[t] = (f32x4){b2v[t], b2v[t], b2v[t], b2v[t]};
#pragma unroll
        for (int s = 0; s < 2; ++s)
#pragma unroll
            for (int t = 0; t < 2; ++t)
                acc2[t] = __builtin_amdgcn_mfma_f32_16x16x32_bf16(a2[s], w2f[s][t], acc2[t], 0, 0, 0);

#pragma unroll
        for (int t = 0; t < 2; ++t)
#pragma unroll
            for (int r = 0; r < 4; ++r) {
                int er = ebase + 4 * q + r;
                if (er < E) e_out[(size_t)er * 32 + 16 * t + n] = acc2[t][r];
            }
    }
}

// ---------------- node model (MFMA): x' = MLP([x, aggm, u[batch]]) in-place ----------------
__global__ __launch_bounds__(256) void node_mfma(
    float* __restrict__ x, const float* __restrict__ aggm, const float* __restrict__ u,
    const int* __restrict__ batch,
    const float* __restrict__ W1, const float* __restrict__ b1,
    const float* __restrict__ W2, const float* __restrict__ b2, int N) {
    __shared__ short hbuf[4][16 * 72];
    const int tid = threadIdx.x;
    const int wv = tid >> 6, lane = tid & 63;
    const int n = lane & 15, q = lane >> 4;

    bf16x8 w1f[3][4];
#pragma unroll
    for (int s = 0; s < 3; ++s)
#pragma unroll
        for (int t = 0; t < 4; ++t)
#pragma unroll
            for (int j = 0; j < 8; ++j)
                w1f[s][t][j] = f2bf(W1[(32 * s + 8 * q + j) * 64 + 16 * t + n]);
    bf16x8 w2f[2][2];
#pragma unroll
    for (int s = 0; s < 2; ++s)
#pragma unroll
        for (int t = 0; t < 2; ++t)
#pragma unroll
            for (int j = 0; j < 8; ++j)
                w2f[s][t][j] = f2bf(W2[(32 * s + 8 * q + j) * 32 + 16 * t + n]);
    float b1v[4];
#pragma unroll
    for (int t = 0; t < 4; ++t) b1v[t] = b1[16 * t + n];
    float b2v[2];
#pragma unroll
    for (int t = 0; t < 2; ++t) b2v[t] = b2[16 * t + n];

    short* hw = hbuf[wv];
#pragma unroll 1
    for (int t4 = 0; t4 < 4; ++t4) {
        int nbase = blockIdx.x * 256 + wv * 64 + t4 * 16;
        int nidx = min(nbase + n, N - 1);
        int bi = batch[nidx];

        bf16x8 af[3];
        af[0] = load8_bf(x + (size_t)nidx * 32 + 8 * q);
        af[1] = load8_bf(aggm + (size_t)nidx * 32 + 8 * q);
        af[2] = load8_bf(u + (size_t)bi * 32 + 8 * q);

        f32x4 acc[4];
#pragma unroll
        for (int t = 0; t < 4; ++t) acc[t] = (f32x4){b1v[t], b1v[t], b1v[t], b1v[t]};
#pragma unroll
        for (int s = 0; s < 3; ++s)
#pragma unroll
            for (int t = 0; t < 4; ++t)
                acc[t] = __builtin_amdgcn_mfma_f32_16x16x32_bf16(af[s], w1f[s][t], acc[t], 0, 0, 0);

        __syncthreads();
#pragma unroll
        for (int t = 0; t < 4; ++t)
#pragma unroll
            for (int r = 0; r < 4; ++r)
                hw[(4 * q + r) * 72 + 16 * t + n] = f2bf(fmaxf(acc[t][r], 0.0f));
        __syncthreads();

        bf16x8 a2[2];
#pragma unroll
        for (int s = 0; s < 2; ++s)
            a2[s] = *(const bf16x8*)(hw + n * 72 + 32 * s + 8 * q);

        f32x4 acc2[2];
#pragma unroll
        for (int t = 0; t < 2; ++t) acc2[t] = (f32x4){b2v[t], b2v[t], b2v[t], b2v[t]};
#pragma unroll
        for (int s = 0; s < 2; ++s)
#pragma unroll
            for (int t = 0; t < 2; ++t)
                acc2[t] = __builtin_amdgcn_mfma_f32_16x16x32_bf16(a2[s], w2f[s][t], acc2[t], 0, 0, 0);

#pragma unroll
        for (int t = 0; t < 2; ++t)
#pragma unroll
            for (int r = 0; r < 4; ++r) {
                int nr = nbase + 4 * q + r;
                if (nr < N) x[(size_t)nr * 32 + 16 * t + n] = acc2[t][r];
            }
    }
}

// ---------------- xg = scatter_mean(x' -> batch), batch sorted ----------------
__device__ __forceinline__ int lbound(const int* __restrict__ a, int nn, int v) {
    int lo = 0, hi = nn;
    while (lo < hi) {
        int mid = (lo + hi) >> 1;
        if (a[mid] < v) lo = mid + 1; else hi = mid;
    }
    return lo;
}

__global__ void xg_kernel(const float* __restrict__ xp, const int* __restrict__ batch, int N,
                          float* __restrict__ xgm) {
    int b = blockIdx.x;
    __shared__ int s_lo, s_hi;
    if (threadIdx.x == 0) {
        s_lo = lbound(batch, N, b);
        s_hi = lbound(batch, N, b + 1);
    }
    __syncthreads();
    int lo = s_lo, hi = s_hi;
    int c = threadIdx.x & 31;
    int g = threadIdx.x >> 5;  // 8 groups
    float acc = 0.0f;
    for (int i = lo + g; i < hi; i += 8) acc += xp[(size_t)i * 32 + c];
    __shared__ float red[256];
    red[threadIdx.x] = acc;
    __syncthreads();
    if (g == 0) {
        float sum = 0.0f;
#pragma unroll
        for (int k = 0; k < 8; ++k) sum += red[k * 32 + c];
        xgm[b * 32 + c] = sum / fmaxf((float)(hi - lo), 1.0f);
    }
}

// ---------------- global model: u' = MLP([u, xgm]) (fp32, exact) ----------------
__global__ void glob_kernel(const float* __restrict__ u, const float* __restrict__ xgm,
                            const float* __restrict__ W1, const float* __restrict__ b1,
                            const float* __restrict__ W2, const float* __restrict__ b2,
                            float* __restrict__ u_dst) {
    int r = blockIdx.x;
    int t = threadIdx.x;  // 64 threads
    __shared__ float gin[64];
    __shared__ float hs[64];
    if (t < 32)
        gin[t] = u[r * 32 + t];
    else
        gin[t] = xgm[r * 32 + (t - 32)];
    __syncthreads();
    float h = b1[t];
#pragma unroll
    for (int k = 0; k < 64; ++k) h = fmaf(gin[k], W1[k * 64 + t], h);
    hs[t] = fmaxf(h, 0.0f);
    __syncthreads();
    if (t < 32) {
        float o = b2[t];
#pragma unroll
        for (int k = 0; k < 64; ++k) o = fmaf(hs[k], W2[k * 32 + t], o);
        u_dst[r * 32 + t] = o;
    }
}

extern "C" void kernel_launch(void* const* d_in, const int* in_sizes, int n_in,
                              void* d_out, int out_size, void* d_ws, size_t ws_size,
                              hipStream_t stream) {
    const float* node_feats = (const float*)d_in[0];
    const int* edge_index = (const int*)d_in[1];
    const float* edge_feats = (const float*)d_in[2];
    const float* glob_feats = (const float*)d_in[3];
    const int* batch = (const int*)d_in[4];
    const float* node_gamma = (const float*)d_in[5];
    const float* node_beta = (const float*)d_in[6];
    const float* edge_gamma = (const float*)d_in[7];
    const float* edge_beta = (const float*)d_in[8];
    const float* glob_gamma = (const float*)d_in[9];
    const float* glob_beta = (const float*)d_in[10];
    const float* edge_W1 = (const float*)d_in[11];
    const float* edge_b1 = (const float*)d_in[12];
    const float* edge_W2 = (const float*)d_in[13];
    const float* edge_b2 = (const float*)d_in[14];
    const float* node_W1 = (const float*)d_in[15];
    const float* node_b1 = (const float*)d_in[16];
    const float* node_W2 = (const float*)d_in[17];
    const float* node_b2 = (const float*)d_in[18];
    const float* glob_W1 = (const float*)d_in[19];
    const float* glob_b1 = (const float*)d_in[20];
    const float* glob_W2 = (const float*)d_in[21];
    const float* glob_b2 = (const float*)d_in[22];

    const int N = in_sizes[0] / 32;
    const int E = in_sizes[1] / 2;
    const int B = in_sizes[3] / 32;

    float* x_out = (float*)d_out;           // N x 32
    float* e_out = x_out + (size_t)N * 32;  // E x 32
    float* u_out = e_out + (size_t)E * 32;  // B x 32

    char* ws = (char*)d_ws;
    float* aggm = (float*)ws;   ws += (size_t)N * 32 * 4;   // 16B aligned
    int* csr_eid = (int*)ws;    ws += (size_t)E * 4;
    int* csr_row = (int*)ws;    ws += (size_t)(N + 1) * 4;
    int* cursor = (int*)ws;     ws += (size_t)N * 4;
    int* hist = (int*)ws;       ws += (size_t)N * 4;
    float* xgm = (float*)ws;    ws += (size_t)B * 32 * 4;
    float* u_buf = (float*)ws;  ws += (size_t)B * 32 * 4;

    const int* ei_src = edge_index;
    const int* ei_dst = edge_index + E;

    // input norms
    bn_kernel<<<(N * 8 + 255) / 256, 256, 0, stream>>>(node_feats, node_gamma, node_beta, x_out, N * 8);
    bn_kernel<<<(B * 8 + 255) / 256, 256, 0, stream>>>(glob_feats, glob_gamma, glob_beta, u_buf, B * 8);

    // CSR build (structure fixed across layers)
    hipMemsetAsync(hist, 0, (size_t)N * 4, stream);
    hist_kernel<<<(E + 255) / 256, 256, 0, stream>>>(ei_dst, hist, E);
    scan_kernel<<<1, 1024, 0, stream>>>(hist, csr_row, N);
    hipMemcpyAsync(cursor, csr_row, (size_t)N * 4, hipMemcpyDeviceToDevice, stream);
    scatter_kernel<<<(E + 255) / 256, 256, 0, stream>>>(ei_dst, cursor, csr_eid, E);

    for (int l = 0; l < 3; ++l) {
        edge_mfma<<<(E + 255) / 256, 256, 0, stream>>>(
            x_out, (l == 0) ? edge_feats : e_out, e_out, u_buf, ei_src, ei_dst, batch,
            edge_W1 + (size_t)l * 128 * 64, edge_b1 + l * 64,
            edge_W2 + (size_t)l * 64 * 32, edge_b2 + l * 32,
            edge_gamma, edge_beta, (l == 0) ? 1 : 0, E);
        agg_kernel<<<(N * 8 + 255) / 256, 256, 0, stream>>>(csr_row, csr_eid, e_out, aggm, N);
        node_mfma<<<(N + 255) / 256, 256, 0, stream>>>(
            x_out, aggm, u_buf, batch,
            node_W1 + (size_t)l * 96 * 64, node_b1 + l * 64,
            node_W2 + (size_t)l * 64 * 32, node_b2 + l * 32, N);
        xg_kernel<<<B, 256, 0, stream>>>(x_out, batch, N, xgm);
        glob_kernel<<<B, 64, 0, stream>>>(
            u_buf, xgm,
            glob_W1 + (size_t)l * 64 * 64, glob_b1 + l * 64,
            glob_W2 + (size_t)l * 64 * 32, glob_b2 + l * 32,
            (l == 2) ? u_out : u_buf);
    }
}

// Round 3
// 922.696 us; speedup vs baseline: 10.2051x; 1.1877x over previous
//
#include <hip/hip_runtime.h>
#include <cstddef>

#define BN_RS 0.99999500003749971f  // 1/sqrt(1+1e-5)

typedef __attribute__((ext_vector_type(8))) short bf16x8;
typedef __attribute__((ext_vector_type(4))) short bf16x4;
typedef __attribute__((ext_vector_type(4))) float f32x4;

#define LGKM0() asm volatile("s_waitcnt lgkmcnt(0)" ::: "memory")

__device__ __forceinline__ short f2bf(float f) {
    union { float f; unsigned u; } c; c.f = f;
    unsigned r = (c.u + 0x7fffu + ((c.u >> 16) & 1u)) >> 16;
    return (short)r;
}
__device__ __forceinline__ float bf2f(unsigned short h) {
    union { unsigned u; float f; } c; c.u = ((unsigned)h) << 16;
    return c.f;
}
__device__ __forceinline__ bf16x8 load8_bf(const float* __restrict__ p) {
    float4 a = *(const float4*)p;
    float4 b = *(const float4*)(p + 4);
    bf16x8 r;
    r[0] = f2bf(a.x); r[1] = f2bf(a.y); r[2] = f2bf(a.z); r[3] = f2bf(a.w);
    r[4] = f2bf(b.x); r[5] = f2bf(b.y); r[6] = f2bf(b.z); r[7] = f2bf(b.w);
    return r;
}

// ---------------- BN -> bf16 (node feats) ----------------
__global__ void bn_x_kernel(const float* __restrict__ in, const float* __restrict__ gamma,
                            const float* __restrict__ beta, unsigned short* __restrict__ xbf, int n4) {
    int i = blockIdx.x * blockDim.x + threadIdx.x;
    if (i >= n4) return;
    float4 v = ((const float4*)in)[i];
    float4 g = ((const float4*)gamma)[i & 7];
    float4 b = ((const float4*)beta)[i & 7];
    bf16x4 o;
    o[0] = f2bf(fmaf(v.x, g.x * BN_RS, b.x));
    o[1] = f2bf(fmaf(v.y, g.y * BN_RS, b.y));
    o[2] = f2bf(fmaf(v.z, g.z * BN_RS, b.z));
    o[3] = f2bf(fmaf(v.w, g.w * BN_RS, b.w));
    *(bf16x4*)(xbf + (size_t)i * 4) = o;
}

// ---------------- BN -> fp32 + bf16 (globals) ----------------
__global__ void bn_u_kernel(const float* __restrict__ in, const float* __restrict__ gamma,
                            const float* __restrict__ beta, float* __restrict__ ubuf,
                            unsigned short* __restrict__ ubf, int n4) {
    int i = blockIdx.x * blockDim.x + threadIdx.x;
    if (i >= n4) return;
    float4 v = ((const float4*)in)[i];
    float4 g = ((const float4*)gamma)[i & 7];
    float4 b = ((const float4*)beta)[i & 7];
    v.x = fmaf(v.x, g.x * BN_RS, b.x);
    v.y = fmaf(v.y, g.y * BN_RS, b.y);
    v.z = fmaf(v.z, g.z * BN_RS, b.z);
    v.w = fmaf(v.w, g.w * BN_RS, b.w);
    ((float4*)ubuf)[i] = v;
    bf16x4 o;
    o[0] = f2bf(v.x); o[1] = f2bf(v.y); o[2] = f2bf(v.z); o[3] = f2bf(v.w);
    *(bf16x4*)(ubf + (size_t)i * 4) = o;
}

// ---------------- CSR build ----------------
__global__ void hist_kernel(const int* __restrict__ idx, int* __restrict__ cnt, int n) {
    int i = blockIdx.x * blockDim.x + threadIdx.x;
    if (i < n) atomicAdd(&cnt[idx[i]], 1);
}

__global__ void scan_kernel(const int* __restrict__ cnt, int* __restrict__ row, int N) {
    __shared__ int sd[1024];
    int tid = threadIdx.x;
    int chunk = (N + 1023) >> 10;
    int lo = tid * chunk, hi = min(lo + chunk, N);
    int s = 0;
    for (int i = lo; i < hi; ++i) s += cnt[i];
    sd[tid] = s;
    __syncthreads();
    for (int off = 1; off < 1024; off <<= 1) {
        int t = (tid >= off) ? sd[tid - off] : 0;
        __syncthreads();
        sd[tid] += t;
        __syncthreads();
    }
    int run = sd[tid] - s;  // exclusive prefix
    for (int i = lo; i < hi; ++i) { row[i] = run; run += cnt[i]; }
    if (tid == 1023) row[N] = sd[1023];
}

__global__ void scatter_kernel(const int* __restrict__ dst, int* __restrict__ cursor,
                               int* __restrict__ eid, int E) {
    int e = blockIdx.x * blockDim.x + threadIdx.x;
    if (e < E) {
        int d = dst[e];
        int slot = atomicAdd(&cursor[d], 1);
        eid[slot] = e;
    }
}

__global__ void batch_src_kernel(const int* __restrict__ src, const int* __restrict__ batch,
                                 int* __restrict__ be, int E) {
    int e = blockIdx.x * blockDim.x + threadIdx.x;
    if (e < E) be[e] = batch[src[e]];
}

// ---------------- agg = scatter_mean(e' -> dst), CSR gather, bf16 out ----------------
__global__ void agg_kernel(const int* __restrict__ row, const int* __restrict__ eid,
                           const unsigned short* __restrict__ ebf, const float* __restrict__ ef,
                           int use_f32, unsigned short* __restrict__ aggbf, int N) {
    int t = blockIdx.x * blockDim.x + threadIdx.x;
    int node = t >> 3;
    if (node >= N) return;
    int c = (t & 7) * 4;
    int s = row[node], e = row[node + 1];
    float a0 = 0.f, a1 = 0.f, a2 = 0.f, a3 = 0.f;
    if (use_f32) {
        for (int j = s; j < e; ++j) {
            int ed = eid[j];
            float4 v = *(const float4*)(ef + (size_t)ed * 32 + c);
            a0 += v.x; a1 += v.y; a2 += v.z; a3 += v.w;
        }
    } else {
        for (int j = s; j < e; ++j) {
            int ed = eid[j];
            ushort4 v = *(const ushort4*)(ebf + (size_t)ed * 32 + c);
            a0 += bf2f(v.x); a1 += bf2f(v.y); a2 += bf2f(v.z); a3 += bf2f(v.w);
        }
    }
    float inv = 1.0f / fmaxf((float)(e - s), 1.0f);
    bf16x4 o;
    o[0] = f2bf(a0 * inv); o[1] = f2bf(a1 * inv); o[2] = f2bf(a2 * inv); o[3] = f2bf(a3 * inv);
    *(bf16x4*)(aggbf + (size_t)node * 32 + c) = o;
}

// ---------------- edge model (MFMA) ----------------
// in_fmt: 0 = fp32 input with BN folded into weights (layer 0), 1 = bf16 input, 2 = plain fp32
// out_f32: 1 -> write fp32 eout_f, else bf16 eout_b
__global__ __launch_bounds__(256) void edge_mfma(
    const unsigned short* __restrict__ xbf,
    const float* __restrict__ ein_f, const unsigned short* __restrict__ ein_b,
    unsigned short* __restrict__ eout_b, float* __restrict__ eout_f,
    const unsigned short* __restrict__ ubf,
    const int* __restrict__ src, const int* __restrict__ dstp, const int* __restrict__ bsrc,
    const float* __restrict__ W1, const float* __restrict__ b1,
    const float* __restrict__ W2, const float* __restrict__ b2,
    const float* __restrict__ egam, const float* __restrict__ ebet,
    int in_fmt, int out_f32, int E) {
    __shared__ unsigned short hbuf[4][16 * 72];
    const int tid = threadIdx.x;
    const int wv = tid >> 6, lane = tid & 63;
    const int n = lane & 15, q = lane >> 4;

    float eg[8];
    if (in_fmt == 0) {
#pragma unroll
        for (int j = 0; j < 8; ++j) eg[j] = egam[8 * q + j] * BN_RS;
    }

    bf16x8 w1f[4][4];
#pragma unroll
    for (int s = 0; s < 4; ++s)
#pragma unroll
        for (int t = 0; t < 4; ++t)
#pragma unroll
            for (int j = 0; j < 8; ++j) {
                float w = W1[(32 * s + 8 * q + j) * 64 + 16 * t + n];
                if (in_fmt == 0 && s == 2) w *= eg[j];
                w1f[s][t][j] = f2bf(w);
            }
    bf16x8 w2f[2][2];
#pragma unroll
    for (int s = 0; s < 2; ++s)
#pragma unroll
        for (int t = 0; t < 2; ++t)
#pragma unroll
            for (int j = 0; j < 8; ++j)
                w2f[s][t][j] = f2bf(W2[(32 * s + 8 * q + j) * 32 + 16 * t + n]);
    float b1v[4];
#pragma unroll
    for (int t = 0; t < 4; ++t) {
        float bb = b1[16 * t + n];
        if (in_fmt == 0) {
            for (int k = 0; k < 32; ++k) bb = fmaf(ebet[k], W1[(64 + k) * 64 + 16 * t + n], bb);
        }
        b1v[t] = bb;
    }
    float b2v[2];
#pragma unroll
    for (int t = 0; t < 2; ++t) b2v[t] = b2[16 * t + n];

    const int base_e = blockIdx.x * 256 + wv * 64;

    auto load_tile = [&](int t4, bf16x8* af) {
        int eidx = min(base_e + t4 * 16 + n, E - 1);
        int si = src[eidx], di = dstp[eidx], bi = bsrc[eidx];
        af[0] = *(const bf16x8*)(xbf + (size_t)si * 32 + 8 * q);
        af[1] = *(const bf16x8*)(xbf + (size_t)di * 32 + 8 * q);
        if (in_fmt == 1)
            af[2] = *(const bf16x8*)(ein_b + (size_t)eidx * 32 + 8 * q);
        else
            af[2] = load8_bf(ein_f + (size_t)eidx * 32 + 8 * q);
        af[3] = *(const bf16x8*)(ubf + (size_t)bi * 32 + 8 * q);
    };

    unsigned short* hw = hbuf[wv];
    bf16x8 afb[2][4];
    load_tile(0, afb[0]);

#pragma unroll
    for (int t4 = 0; t4 < 4; ++t4) {
        bf16x8* af = afb[t4 & 1];
        if (t4 < 3) load_tile(t4 + 1, afb[(t4 + 1) & 1]);

        f32x4 acc[4];
#pragma unroll
        for (int t = 0; t < 4; ++t) acc[t] = (f32x4){b1v[t], b1v[t], b1v[t], b1v[t]};
#pragma unroll
        for (int s = 0; s < 4; ++s)
#pragma unroll
            for (int t = 0; t < 4; ++t)
                acc[t] = __builtin_amdgcn_mfma_f32_16x16x32_bf16(af[s], w1f[s][t], acc[t], 0, 0, 0);

        LGKM0();  // per-wave hbuf: prior reads drained (DS is in-order per wave) + compiler barrier
#pragma unroll
        for (int t = 0; t < 4; ++t)
#pragma unroll
            for (int r = 0; r < 4; ++r)
                hw[(4 * q + r) * 72 + 16 * t + n] = (unsigned short)f2bf(fmaxf(acc[t][r], 0.0f));
        LGKM0();  // writes visible to all lanes of this wave

        bf16x8 a2[2];
#pragma unroll
        for (int s = 0; s < 2; ++s)
            a2[s] = *(const bf16x8*)(hw + n * 72 + 32 * s + 8 * q);

        f32x4 acc2[2];
#pragma unroll
        for (int t = 0; t < 2; ++t) acc2[t] = (f32x4){b2v[t], b2v[t], b2v[t], b2v[t]};
#pragma unroll
        for (int s = 0; s < 2; ++s)
#pragma unroll
            for (int t = 0; t < 2; ++t)
                acc2[t] = __builtin_amdgcn_mfma_f32_16x16x32_bf16(a2[s], w2f[s][t], acc2[t], 0, 0, 0);

        int erow = base_e + t4 * 16 + 4 * q;
#pragma unroll
        for (int t = 0; t < 2; ++t)
#pragma unroll
            for (int r = 0; r < 4; ++r) {
                int er = erow + r;
                if (er < E) {
                    if (out_f32)
                        eout_f[(size_t)er * 32 + 16 * t + n] = acc2[t][r];
                    else
                        eout_b[(size_t)er * 32 + 16 * t + n] = (unsigned short)f2bf(acc2[t][r]);
                }
            }
    }
}

// ---------------- node model (MFMA): x' = MLP([x, agg, u[batch]]) ----------------
__global__ __launch_bounds__(256) void node_mfma(
    unsigned short* __restrict__ xbf, const unsigned short* __restrict__ aggbf,
    const unsigned short* __restrict__ ubf, const int* __restrict__ batch,
    const float* __restrict__ W1, const float* __restrict__ b1,
    const float* __restrict__ W2, const float* __restrict__ b2,
    float* __restrict__ xf_out, int write_f32, int N) {
    __shared__ unsigned short hbuf[4][16 * 72];
    const int tid = threadIdx.x;
    const int wv = tid >> 6, lane = tid & 63;
    const int n = lane & 15, q = lane >> 4;

    bf16x8 w1f[3][4];
#pragma unroll
    for (int s = 0; s < 3; ++s)
#pragma unroll
        for (int t = 0; t < 4; ++t)
#pragma unroll
            for (int j = 0; j < 8; ++j)
                w1f[s][t][j] = f2bf(W1[(32 * s + 8 * q + j) * 64 + 16 * t + n]);
    bf16x8 w2f[2][2];
#pragma unroll
    for (int s = 0; s < 2; ++s)
#pragma unroll
        for (int t = 0; t < 2; ++t)
#pragma unroll
            for (int j = 0; j < 8; ++j)
                w2f[s][t][j] = f2bf(W2[(32 * s + 8 * q + j) * 32 + 16 * t + n]);
    float b1v[4];
#pragma unroll
    for (int t = 0; t < 4; ++t) b1v[t] = b1[16 * t + n];
    float b2v[2];
#pragma unroll
    for (int t = 0; t < 2; ++t) b2v[t] = b2[16 * t + n];

    const int base_n = blockIdx.x * 256 + wv * 64;

    auto load_tile = [&](int t4, bf16x8* af) {
        int nidx = min(base_n + t4 * 16 + n, N - 1);
        int bi = batch[nidx];
        af[0] = *(const bf16x8*)(xbf + (size_t)nidx * 32 + 8 * q);
        af[1] = *(const bf16x8*)(aggbf + (size_t)nidx * 32 + 8 * q);
        af[2] = *(const bf16x8*)(ubf + (size_t)bi * 32 + 8 * q);
    };

    unsigned short* hw = hbuf[wv];
    bf16x8 afb[2][3];
    load_tile(0, afb[0]);

#pragma unroll
    for (int t4 = 0; t4 < 4; ++t4) {
        bf16x8* af = afb[t4 & 1];
        if (t4 < 3) load_tile(t4 + 1, afb[(t4 + 1) & 1]);

        f32x4 acc[4];
#pragma unroll
        for (int t = 0; t < 4; ++t) acc[t] = (f32x4){b1v[t], b1v[t], b1v[t], b1v[t]};
#pragma unroll
        for (int s = 0; s < 3; ++s)
#pragma unroll
            for (int t = 0; t < 4; ++t)
                acc[t] = __builtin_amdgcn_mfma_f32_16x16x32_bf16(af[s], w1f[s][t], acc[t], 0, 0, 0);

        LGKM0();
#pragma unroll
        for (int t = 0; t < 4; ++t)
#pragma unroll
            for (int r = 0; r < 4; ++r)
                hw[(4 * q + r) * 72 + 16 * t + n] = (unsigned short)f2bf(fmaxf(acc[t][r], 0.0f));
        LGKM0();

        bf16x8 a2[2];
#pragma unroll
        for (int s = 0; s < 2; ++s)
            a2[s] = *(const bf16x8*)(hw + n * 72 + 32 * s + 8 * q);

        f32x4 acc2[2];
#pragma unroll
        for (int t = 0; t < 2; ++t) acc2[t] = (f32x4){b2v[t], b2v[t], b2v[t], b2v[t]};
#pragma unroll
        for (int s = 0; s < 2; ++s)
#pragma unroll
            for (int t = 0; t < 2; ++t)
                acc2[t] = __builtin_amdgcn_mfma_f32_16x16x32_bf16(a2[s], w2f[s][t], acc2[t], 0, 0, 0);

        int nrow = base_n + t4 * 16 + 4 * q;
#pragma unroll
        for (int t = 0; t < 2; ++t)
#pragma unroll
            for (int r = 0; r < 4; ++r) {
                int nr = nrow + r;
                if (nr < N) {
                    xbf[(size_t)nr * 32 + 16 * t + n] = (unsigned short)f2bf(acc2[t][r]);
                    if (write_f32) xf_out[(size_t)nr * 32 + 16 * t + n] = acc2[t][r];
                }
            }
    }
}

// ---------------- xg partial sums (batch sorted): atomicAdd per segment-flush ----------------
__global__ void xg_kernel(const unsigned short* __restrict__ xbf, const int* __restrict__ batch,
                          int N, float* __restrict__ xg) {
    int nblk = gridDim.x;
    int chunk = (N + nblk - 1) / nblk;
    int start = blockIdx.x * chunk;
    int end = min(start + chunk, N);
    int c = threadIdx.x & 31;
    int g = threadIdx.x >> 5;  // 8 node-lanes
    float acc = 0.0f;
    int cur = -1;
    for (int i = start + g; i < end; i += 8) {
        int b = batch[i];
        float v = bf2f(xbf[(size_t)i * 32 + c]);
        if (b != cur) {
            if (cur >= 0) atomicAdd(&xg[cur * 32 + c], acc);
            cur = b; acc = v;
        } else {
            acc += v;
        }
    }
    if (cur >= 0) atomicAdd(&xg[cur * 32 + c], acc);
}

// ---------------- global model: u' = MLP([u, xg/cnt]) ----------------
__device__ __forceinline__ int lbound(const int* __restrict__ a, int nn, int v) {
    int lo = 0, hi = nn;
    while (lo < hi) {
        int mid = (lo + hi) >> 1;
        if (a[mid] < v) lo = mid + 1; else hi = mid;
    }
    return lo;
}

__global__ void glob_kernel(const float* __restrict__ u, const float* __restrict__ xg,
                            const int* __restrict__ batch, int N,
                            const float* __restrict__ W1, const float* __restrict__ b1,
                            const float* __restrict__ W2, const float* __restrict__ b2,
                            float* __restrict__ u_dst, unsigned short* __restrict__ ubf_dst) {
    int r = blockIdx.x;
    int t = threadIdx.x;  // 64 threads
    __shared__ float gin[64];
    __shared__ float hs[64];
    __shared__ int cnts;
    if (t == 0) cnts = lbound(batch, N, r + 1) - lbound(batch, N, r);
    __syncthreads();
    if (t < 32)
        gin[t] = u[r * 32 + t];
    else
        gin[t] = xg[r * 32 + (t - 32)] / fmaxf((float)cnts, 1.0f);
    __syncthreads();
    float h = b1[t];
#pragma unroll
    for (int k = 0; k < 64; ++k) h = fmaf(gin[k], W1[k * 64 + t], h);
    hs[t] = fmaxf(h, 0.0f);
    __syncthreads();
    if (t < 32) {
        float o = b2[t];
#pragma unroll
        for (int k = 0; k < 64; ++k) o = fmaf(hs[k], W2[k * 32 + t], o);
        u_dst[r * 32 + t] = o;
        ubf_dst[r * 32 + t] = (unsigned short)f2bf(o);
    }
}

extern "C" void kernel_launch(void* const* d_in, const int* in_sizes, int n_in,
                              void* d_out, int out_size, void* d_ws, size_t ws_size,
                              hipStream_t stream) {
    const float* node_feats = (const float*)d_in[0];
    const int* edge_index = (const int*)d_in[1];
    const float* edge_feats = (const float*)d_in[2];
    const float* glob_feats = (const float*)d_in[3];
    const int* batch = (const int*)d_in[4];
    const float* node_gamma = (const float*)d_in[5];
    const float* node_beta = (const float*)d_in[6];
    const float* edge_gamma = (const float*)d_in[7];
    const float* edge_beta = (const float*)d_in[8];
    const float* glob_gamma = (const float*)d_in[9];
    const float* glob_beta = (const float*)d_in[10];
    const float* edge_W1 = (const float*)d_in[11];
    const float* edge_b1 = (const float*)d_in[12];
    const float* edge_W2 = (const float*)d_in[13];
    const float* edge_b2 = (const float*)d_in[14];
    const float* node_W1 = (const float*)d_in[15];
    const float* node_b1 = (const float*)d_in[16];
    const float* node_W2 = (const float*)d_in[17];
    const float* node_b2 = (const float*)d_in[18];
    const float* glob_W1 = (const float*)d_in[19];
    const float* glob_b1 = (const float*)d_in[20];
    const float* glob_W2 = (const float*)d_in[21];
    const float* glob_b2 = (const float*)d_in[22];

    const int N = in_sizes[0] / 32;
    const int E = in_sizes[1] / 2;
    const int B = in_sizes[3] / 32;

    float* x_out = (float*)d_out;           // N x 32
    float* e_out = x_out + (size_t)N * 32;  // E x 32
    float* u_out = e_out + (size_t)E * 32;  // B x 32

    // workspace carve (16B-aligned chunks)
    char* ws = (char*)d_ws;
    unsigned short* x_bf = (unsigned short*)ws;  ws += (size_t)N * 32 * 2;
    unsigned short* agg_bf = (unsigned short*)ws; ws += (size_t)N * 32 * 2;
    unsigned short* u_bf = (unsigned short*)ws;  ws += 2048;
    float* u_buf = (float*)ws;                   ws += 4096;
    float* xg = (float*)ws;                      ws += 4096;
    int* eid = (int*)ws;                         ws += (size_t)E * 4;
    int* bsrc = (int*)ws;                        ws += (size_t)E * 4;
    int* rowp = (int*)ws;                        ws += (size_t)(N + 4) * 4;
    int* cursor = (int*)ws;                      ws += (size_t)N * 4;
    int* hist = (int*)ws;                        ws += (size_t)N * 4;
    size_t base_used = (size_t)(ws - (char*)d_ws);
    size_t ebf_bytes = (size_t)E * 32 * 2;
    int use_ebf = (base_used + ebf_bytes + 256 <= ws_size) ? 1 : 0;
    unsigned short* e_bf = use_ebf ? (unsigned short*)ws : (unsigned short*)e_out;  // dummy if unused

    const int* ei_src = edge_index;
    const int* ei_dst = edge_index + E;

    bn_x_kernel<<<(N * 8 + 255) / 256, 256, 0, stream>>>(node_feats, node_gamma, node_beta, x_bf, N * 8);
    bn_u_kernel<<<(B * 8 + 255) / 256, 256, 0, stream>>>(glob_feats, glob_gamma, glob_beta, u_buf, u_bf, B * 8);

    hipMemsetAsync(hist, 0, (size_t)N * 4, stream);
    hist_kernel<<<(E + 255) / 256, 256, 0, stream>>>(ei_dst, hist, E);
    scan_kernel<<<1, 1024, 0, stream>>>(hist, rowp, N);
    hipMemcpyAsync(cursor, rowp, (size_t)N * 4, hipMemcpyDeviceToDevice, stream);
    scatter_kernel<<<(E + 255) / 256, 256, 0, stream>>>(ei_dst, cursor, eid, E);
    batch_src_kernel<<<(E + 255) / 256, 256, 0, stream>>>(ei_src, batch, bsrc, E);

    for (int l = 0; l < 3; ++l) {
        hipMemsetAsync(xg, 0, (size_t)B * 32 * 4, stream);

        int in_fmt, out_f32;
        if (use_ebf) {
            in_fmt = (l == 0) ? 0 : 1;
            out_f32 = (l == 2) ? 1 : 0;
        } else {
            in_fmt = (l == 0) ? 0 : 2;
            out_f32 = 1;
        }
        const float* ein_f = (l == 0) ? edge_feats : e_out;

        edge_mfma<<<(E + 255) / 256, 256, 0, stream>>>(
            x_bf, ein_f, e_bf, e_bf, e_out, u_bf, ei_src, ei_dst, bsrc,
            edge_W1 + (size_t)l * 128 * 64, edge_b1 + l * 64,
            edge_W2 + (size_t)l * 64 * 32, edge_b2 + l * 32,
            edge_gamma, edge_beta, in_fmt, out_f32, E);
        agg_kernel<<<(N * 8 + 255) / 256, 256, 0, stream>>>(rowp, eid, e_bf, e_out, out_f32, agg_bf, N);
        node_mfma<<<(N + 255) / 256, 256, 0, stream>>>(
            x_bf, agg_bf, u_bf, batch,
            node_W1 + (size_t)l * 96 * 64, node_b1 + l * 64,
            node_W2 + (size_t)l * 64 * 32, node_b2 + l * 32,
            x_out, (l == 2) ? 1 : 0, N);
        xg_kernel<<<256, 256, 0, stream>>>(x_bf, batch, N, xg);
        glob_kernel<<<B, 64, 0, stream>>>(
            u_buf, xg, batch, N,
            glob_W1 + (size_t)l * 64 * 64, glob_b1 + l * 64,
            glob_W2 + (size_t)l * 64 * 32, glob_b2 + l * 32,
            (l == 2) ? u_out : u_buf, u_bf);
    }
}